// Round 2
// baseline (371.362 us; speedup 1.0000x reference)
//
#include <hip/hip_runtime.h>
#include <hip/hip_bf16.h>

// Problem constants (from reference)
constexpr int Bn   = 16384;   // batch
constexpr int Fn   = 39;      // features per row
constexpr int NUMn = 13;      // masked slots
constexpr int En   = 64;      // embedding dim
constexpr int FDn  = 26000;   // per-feature vocab
constexpr int TV   = Fn * FDn; // 1,014,000 total vocab rows

// ---------------- Phase 1: streaming precompute d[v] = dot(emb[v], w) -------
// 16-lane group per row (float4/lane -> 256 B contiguous per row, 1 KB per
// wave instruction). Each wave handles 16 rows (4 unrolled iterations).
__global__ __launch_bounds__(256) void dot_precompute(
    const float* __restrict__ emb,   // [TV, 64]
    const float* __restrict__ lin_w, // [64]
    float*       __restrict__ d)     // [TV]
{
    const int lane = threadIdx.x & 63;
    const int wid  = (blockIdx.x * blockDim.x + threadIdx.x) >> 6; // global wave
    const int s = lane & 15;   // element chunk
    const int g = lane >> 4;   // row subgroup 0..3

    const float4 w4 = *reinterpret_cast<const float4*>(lin_w + s * 4);
    const int row0 = wid * 16 + g;   // rows row0, row0+4, row0+8, row0+12

    if (row0 + 12 < TV) {
        // fast path: no bounds checks, 4 loads issued back-to-back
#pragma unroll
        for (int i = 0; i < 4; ++i) {
            const int row = row0 + i * 4;
            const float4 v = *reinterpret_cast<const float4*>(emb + row * En + s * 4);
            float p = v.x * w4.x + v.y * w4.y + v.z * w4.z + v.w * w4.w;
            p += __shfl_xor(p, 1, 64);
            p += __shfl_xor(p, 2, 64);
            p += __shfl_xor(p, 4, 64);
            p += __shfl_xor(p, 8, 64);
            if (s == 0) d[row] = p;
        }
    } else {
#pragma unroll
        for (int i = 0; i < 4; ++i) {
            const int row = row0 + i * 4;
            float p = 0.0f;
            if (row < TV) {
                const float4 v = *reinterpret_cast<const float4*>(emb + row * En + s * 4);
                p = v.x * w4.x + v.y * w4.y + v.z * w4.z + v.w * w4.w;
            }
            p += __shfl_xor(p, 1, 64);
            p += __shfl_xor(p, 2, 64);
            p += __shfl_xor(p, 4, 64);
            p += __shfl_xor(p, 8, 64);
            if (s == 0 && row < TV) d[row] = p;
        }
    }
}

// ---------------- Phase 2: per-row gather of d + scale + reduce + sigmoid ---
// One wave per batch row. Lane f (< 39) loads d[feat + f*FD] (4 MB table,
// L2-resident), applies the scatter-multiply scale, 64-lane reduce, sigmoid.
__global__ __launch_bounds__(256) void logits_kernel(
    const int*   __restrict__ features,    // [B*F]
    const int*   __restrict__ mask,        // [B*NUM]
    const unsigned char* __restrict__ mask_apply, // [B*NUM] bool
    const float* __restrict__ mask_value,  // [B*NUM]
    const float* __restrict__ d,           // [TV]
    const float* __restrict__ lin_b,       // [1]
    float*       __restrict__ out)         // [B]
{
    const int lane = threadIdx.x & 63;
    const int row  = blockIdx.x * (blockDim.x >> 6) + (threadIdx.x >> 6);
    if (row >= Bn) return;

    float v = 0.0f;
    if (lane < Fn) {
        const int feat = features[row * Fn + lane];
        const float dv = d[feat + lane * FDn];   // issued before mask loop resolves
        float scale = 1.0f;
#pragma unroll
        for (int n = 0; n < NUMn; ++n) {
            const int   m  = mask[row * NUMn + n];
            const bool  ap = mask_apply[row * NUMn + n] != 0;
            const float mv = mask_value[row * NUMn + n];
            if (m == lane && ap) scale *= mv;    // duplicates compose
        }
        v = scale * dv;
    }
#pragma unroll
    for (int off = 32; off > 0; off >>= 1)
        v += __shfl_down(v, off, 64);

    if (lane == 0) {
        const float logit = v + (float)Fn * lin_b[0];
        out[row] = 1.0f / (1.0f + expf(-logit));
    }
}

extern "C" void kernel_launch(void* const* d_in, const int* in_sizes, int n_in,
                              void* d_out, int out_size, void* d_ws, size_t ws_size,
                              hipStream_t stream) {
    const int*   features   = (const int*)  d_in[0];
    const int*   mask       = (const int*)  d_in[1];
    const unsigned char* mask_apply = (const unsigned char*)d_in[2];
    const float* mask_value = (const float*)d_in[3];
    const float* emb        = (const float*)d_in[4];
    const float* lin_w      = (const float*)d_in[5];
    const float* lin_b      = (const float*)d_in[6];
    float*       out        = (float*)d_out;
    float*       d          = (float*)d_ws;      // 4,056,000 B scratch

    // Phase 1: 16 rows/wave, 4 waves/block -> 64 rows/block
    const int blocks1 = (TV + 63) / 64;          // 15,844
    dot_precompute<<<blocks1, 256, 0, stream>>>(emb, lin_w, d);

    // Phase 2: one wave per batch row
    const int blocks2 = Bn / 4;                  // 4096
    logits_kernel<<<blocks2, 256, 0, stream>>>(
        features, mask, mask_apply, mask_value, d, lin_b, out);
}